// Round 2
// baseline (191.784 us; speedup 1.0000x reference)
//
#include <hip/hip_runtime.h>
#include <math.h>

#define BB 64
#define QQ 32
#define DD 4096
#define EE 300
#define EP 320          // K padded to 320 (pad region of qn is zero)
#define NB 30
#define TD 256          // doc rows per block
#define NDT (DD/TD)     // 16
#define KC 32           // floats per K-chunk
#define NCH (EP/KC)     // 10 chunks
#define NREP 8          // LDS histogram replicas

// ---------------- prep: normalize query rows, gate logits ----------------
__global__ __launch_bounds__(64) void drmm_prep(const float* __restrict__ query,
                                                const float* __restrict__ Wg,
                                                const float* __restrict__ bg,
                                                float* __restrict__ qn,
                                                float* __restrict__ glog) {
    const int row  = blockIdx.x;          // b*32+q
    const int lane = threadIdx.x;         // 0..63
    const float* src = query + (size_t)row * EE;
    float ss = 0.f;
    for (int e = lane; e < EE; e += 64) { float x = src[e]; ss += x * x; }
    for (int o = 1; o < 64; o <<= 1) ss += __shfl_xor(ss, o);
    const float inv = 1.0f / sqrtf(ss);
    float* dst = qn + (size_t)row * EP;
    float gd = 0.f;
    for (int e = lane; e < EE; e += 64) {
        float xq = src[e] * inv;
        dst[e] = xq;
        gd += xq * Wg[e];
    }
    for (int e = EE + lane; e < EP; e += 64) dst[e] = 0.f;   // zero pad 300..319
    for (int o = 1; o < 64; o <<= 1) gd += __shfl_xor(gd, o);
    if (lane == 0) glog[row] = gd + bg[0];
}

// ---------------- main: interaction + histogram ----------------
__global__ __launch_bounds__(256) void drmm_main(const float* __restrict__ doc,
                                                 const int* __restrict__ qlen,
                                                 const float* __restrict__ qn_ws,
                                                 int* __restrict__ ghist) {
    __shared__ __align__(16) float s_qn[QQ * EP];        // 40.96 KB
    __shared__ __align__(16) float s_doc[2][TD * KC];    // 2 x 32 KB
    __shared__ int   s_hist[NREP][QQ][31];               // 31.7 KB (31: bank de-phase)
    __shared__ float s_inv[TD];                          // 1 KB

    const int b     = blockIdx.x / NDT;
    const int dt    = blockIdx.x % NDT;
    const int dbase = dt * TD;
    const int len   = qlen[b];
    if (len == 0) return;                // whole batch row masked: hist stays zero

    const int tid = threadIdx.x;
    const int wv  = tid >> 6;            // wave id = q-group (wave-uniform)
    const int td  = tid & 63;            // d-group
    const bool wactive = (wv * 8) < len; // wave-uniform mask skip

    const float* docb = doc + ((size_t)b * DD + dbase) * EE;

    // stage chunk c of the doc tile into buffer buf (8 global_load_lds x16B per thread)
    auto STAGE = [&](int c, int buf) {
        const int kb = c * KC;
        #pragma unroll
        for (int i = 0; i < 8; ++i) {
            int S   = i * 256 + tid;         // linear 16B slot
            int d   = S >> 3;
            int k4s = S & 7;                 // swizzled slot within row
            int k4l = k4s ^ ((d >> 3) & 7);  // logical k4 (inverse-swizzled source)
            int kg  = kb + 4 * k4l;
            if (kg >= EE) kg = 0;            // redirect pad reads in-bounds (qn pad=0 kills them)
            const float* gp = docb + (size_t)d * EE + kg;
            float* lp = &s_doc[buf][(i * 256 + wv * 64) * 4];   // wave-uniform LDS base
            __builtin_amdgcn_global_load_lds(
                (const __attribute__((address_space(1))) void*)gp,
                (__attribute__((address_space(3))) void*)lp, 16, 0, 0);
        }
    };

    STAGE(0, 0);

    // stage qn[b] (linear copy; reads are broadcasts so no swizzle needed)
    {
        const float4* qsrc = (const float4*)(qn_ws + (size_t)b * QQ * EP);
        float4* qdst = (float4*)s_qn;
        for (int s = tid; s < QQ * EP / 4; s += 256) qdst[s] = qsrc[s];
    }
    for (int s = tid; s < NREP * QQ * 31; s += 256) ((int*)s_hist)[s] = 0;

    float acc[8][4];
    #pragma unroll
    for (int i = 0; i < 8; ++i)
        #pragma unroll
        for (int j = 0; j < 4; ++j) acc[i][j] = 0.f;

    float ssq = 0.f;                     // norm^2 of row d = tid
    const int fr = (tid >> 3) & 7;       // swizzle key for norm row
    const int fd = (td >> 1) & 7;        // swizzle key for this thread's 4 d-rows
    int cur = 0;

    for (int c = 0; c < NCH; ++c) {
        if (c + 1 < NCH) {
            STAGE(c + 1, cur ^ 1);
            asm volatile("s_waitcnt vmcnt(8) lgkmcnt(0)" ::: "memory");
        } else {
            asm volatile("s_waitcnt vmcnt(0) lgkmcnt(0)" ::: "memory");
        }
        __builtin_amdgcn_s_barrier();

        // norm partial: one row per thread; skip pad slots of last chunk
        {
            const int kmax = (c == NCH - 1) ? 3 : 8;
            const float* rowp = &s_doc[cur][tid * KC];
            #pragma unroll
            for (int k4 = 0; k4 < 8; ++k4) {
                if (k4 < kmax) {
                    float4 v = *(const float4*)(rowp + 4 * (k4 ^ fr));
                    ssq += v.x * v.x + v.y * v.y + v.z * v.z + v.w * v.w;
                }
            }
        }

        if (wactive) {
            #pragma unroll
            for (int k4 = 0; k4 < 8; ++k4) {
                float4 dv[4];
                #pragma unroll
                for (int j = 0; j < 4; ++j)
                    dv[j] = *(const float4*)&s_doc[cur][(td * 4 + j) * KC + 4 * (k4 ^ fd)];
                #pragma unroll
                for (int i = 0; i < 8; ++i) {
                    float4 qv = *(const float4*)&s_qn[(wv * 8 + i) * EP + c * KC + 4 * k4];
                    #pragma unroll
                    for (int j = 0; j < 4; ++j) {
                        acc[i][j] += qv.x * dv[j].x;
                        acc[i][j] += qv.y * dv[j].y;
                        acc[i][j] += qv.z * dv[j].z;
                        acc[i][j] += qv.w * dv[j].w;
                    }
                }
            }
        }
        __builtin_amdgcn_s_barrier();    // all reads of 'cur' done before it is re-staged
        cur ^= 1;
    }

    s_inv[tid] = 1.0f / sqrtf(ssq);
    __syncthreads();

    if (wactive) {
        const int rep = tid & (NREP - 1);
        #pragma unroll
        for (int i = 0; i < 8; ++i) {
            const int q = wv * 8 + i;
            if (q < len) {                       // wave-uniform branch
                #pragma unroll
                for (int j = 0; j < 4; ++j) {
                    float sim = acc[i][j] * s_inv[td * 4 + j];
                    int bin = (int)floorf((sim + 1.0f) * 15.0f);
                    bin = bin < 0 ? 0 : (bin > 29 ? 29 : bin);
                    atomicAdd(&s_hist[rep][q][bin], 1);
                }
            }
        }
    }
    __syncthreads();

    for (int s = tid; s < QQ * NB; s += 256) {
        const int q = s / NB, bin = s % NB;
        int tot = 0;
        #pragma unroll
        for (int r = 0; r < NREP; ++r) tot += s_hist[r][q][bin];
        if (tot) atomicAdd(&ghist[((size_t)b * QQ + q) * NB + bin], tot);
    }
}

// ---------------- final: log1p + FFN + softmax gate + weighted sum ----------------
__global__ __launch_bounds__(64) void drmm_final(const int* __restrict__ ghist,
                                                 const float* __restrict__ glog,
                                                 const float* __restrict__ W1,
                                                 const float* __restrict__ b1,
                                                 const float* __restrict__ W2,
                                                 const float* __restrict__ b2,
                                                 const float* __restrict__ W3,
                                                 const float* __restrict__ b3,
                                                 float* __restrict__ out) {
    const int b = blockIdx.x;
    const int lane = threadIdx.x;       // 0..63, lanes 0..31 carry q
    float z = 0.f, lg = -1e30f;
    if (lane < QQ) {
        const int* hrow = ghist + ((size_t)b * QQ + lane) * NB;
        float h[NB];
        #pragma unroll
        for (int v = 0; v < NB; ++v) h[v] = log1pf((float)hrow[v]);
        float t1[5];
        #pragma unroll
        for (int u = 0; u < 5; ++u) {
            float s = b1[u];
            #pragma unroll
            for (int v = 0; v < NB; ++v) s += W1[u * NB + v] * h[v];
            t1[u] = tanhf(s);
        }
        float s2 = b2[0];
        #pragma unroll
        for (int u = 0; u < 5; ++u) s2 += W2[u] * t1[u];
        z = tanhf(W3[0] * tanhf(s2) + b3[0]);
        lg = glog[b * QQ + lane];
    }
    // softmax over lanes 0..31 (xor masks <32 stay within the 32-lane half)
    float m = lg;
    for (int o = 16; o >= 1; o >>= 1) m = fmaxf(m, __shfl_xor(m, o));
    float e = (lane < QQ) ? expf(lg - m) : 0.f;
    float s = e;
    for (int o = 16; o >= 1; o >>= 1) s += __shfl_xor(s, o);
    float w = z * (e / s);
    for (int o = 16; o >= 1; o >>= 1) w += __shfl_xor(w, o);
    if (lane == 0) out[b] = w;
}

extern "C" void kernel_launch(void* const* d_in, const int* in_sizes, int n_in,
                              void* d_out, int out_size, void* d_ws, size_t ws_size,
                              hipStream_t stream) {
    const float* query = (const float*)d_in[0];
    const float* doc   = (const float*)d_in[1];
    const int*   qlen  = (const int*)d_in[2];
    const float* W1    = (const float*)d_in[3];
    const float* b1    = (const float*)d_in[4];
    const float* W2    = (const float*)d_in[5];
    const float* b2    = (const float*)d_in[6];
    const float* W3    = (const float*)d_in[7];
    const float* b3    = (const float*)d_in[8];
    const float* Wg    = (const float*)d_in[9];
    const float* bg    = (const float*)d_in[10];
    float* out = (float*)d_out;

    float* qn   = (float*)d_ws;                       // [64][32][320]
    float* glog = qn + (size_t)BB * QQ * EP;          // [2048]
    int*   hist = (int*)(glog + BB * QQ);             // [64][32][30]

    hipMemsetAsync(hist, 0, (size_t)BB * QQ * NB * sizeof(int), stream);
    hipLaunchKernelGGL(drmm_prep, dim3(BB * QQ), dim3(64), 0, stream,
                       query, Wg, bg, qn, glog);
    hipLaunchKernelGGL(drmm_main, dim3(BB * NDT), dim3(256), 0, stream,
                       doc, qlen, qn, hist);
    hipLaunchKernelGGL(drmm_final, dim3(BB), dim3(64), 0, stream,
                       hist, glog, W1, b1, W2, b2, W3, b3, out);
}